// Round 1
// baseline (500.585 us; speedup 1.0000x reference)
//
#include <hip/hip_runtime.h>
#include <hip/hip_bf16.h>

#define B_ROWS 1024
#define V_DIM 50257
#define E_DIM 128
#define V_PAD 50304  // 1572 * 32, >= V_DIM, covers GEMM tail tile reads

typedef __attribute__((ext_vector_type(8))) short short8;
typedef __attribute__((ext_vector_type(4))) float float4v;

// ---------------------------------------------------------------------------
// K0: transpose + cast embed2vocab [E][V] fp32 -> e2vT [V_PAD][E] bf16
// ---------------------------------------------------------------------------
__global__ void k0_transpose(const float* __restrict__ e2v,
                             __hip_bfloat16* __restrict__ e2vT) {
    __shared__ float t[32][33];
    const int v0 = blockIdx.x * 32;
    const int k0 = blockIdx.y * 32;
    const int c = threadIdx.x & 31;
    const int r = threadIdx.x >> 5;  // 0..7
#pragma unroll
    for (int i = 0; i < 4; ++i) {
        const int k = k0 + r + i * 8;
        const int v = v0 + c;
        t[r + i * 8][c] = (v < V_DIM) ? e2v[(size_t)k * V_DIM + v] : 0.0f;
    }
    __syncthreads();
#pragma unroll
    for (int i = 0; i < 4; ++i) {
        const int rv = r + i * 8;
        e2vT[(size_t)(v0 + rv) * E_DIM + k0 + c] = __float2bfloat16(t[c][rv]);
    }
}

// ---------------------------------------------------------------------------
// K1: xsembeds[b][:] = sum_v xs[b][v] * EMBEDM[v][:]   (xs rows have <=8 nnz)
// one block per row; scan row for nonzeros, then gather-accumulate.
// ---------------------------------------------------------------------------
__global__ void k1_embed(const float* __restrict__ xs,
                         const float* __restrict__ EM,
                         __hip_bfloat16* __restrict__ xse) {
    const int b = blockIdx.x;
    const int tid = threadIdx.x;
    __shared__ int nzv[64];
    __shared__ float nzval[64];
    __shared__ int nzcount;
    if (tid == 0) nzcount = 0;
    __syncthreads();

    const size_t base = (size_t)b * V_DIM;
    auto note = [&](int v, float val) {
        if (val != 0.0f) {
            int s = atomicAdd(&nzcount, 1);
            if (s < 64) { nzv[s] = v; nzval[s] = val; }
        }
    };

    // alignment head (row start not 16B aligned in general)
    const int h = (int)((4 - (base & 3)) & 3);
    if (tid < h) note(tid, xs[base + tid]);
    // float4 body
    const int n4 = (V_DIM - h) >> 2;
    const float4* xv = reinterpret_cast<const float4*>(xs + base + h);
    for (int j = tid; j < n4; j += 256) {
        float4 x = xv[j];
        if (x.x != 0.0f || x.y != 0.0f || x.z != 0.0f || x.w != 0.0f) {
            const int v = h + 4 * j;
            note(v + 0, x.x);
            note(v + 1, x.y);
            note(v + 2, x.z);
            note(v + 3, x.w);
        }
    }
    // tail
    for (int i = h + n4 * 4 + tid; i < V_DIM; i += 256) note(i, xs[base + i]);
    __syncthreads();

    int cnt = nzcount;
    if (cnt > 64) cnt = 64;
    if (tid < E_DIM) {
        float a = 0.0f;
        for (int s = 0; s < cnt; ++s)
            a += nzval[s] * EM[(size_t)nzv[s] * E_DIM + tid];
        xse[(size_t)b * E_DIM + tid] = __float2bfloat16(a);
    }
}

// ---------------------------------------------------------------------------
// K2: logits = xsembeds @ embed2vocab  via bf16 MFMA 16x16x32.
// Block tile: 128 rows x 64 cols, K = 128 (full). 4 waves, each 32x64.
// LDS stride 136 elems (272 B = 17*16 B): 16B-aligned b128 reads, 2-way
// bank aliasing only (free).
// ---------------------------------------------------------------------------
__global__ __launch_bounds__(256) void k2_gemm(
        const __hip_bfloat16* __restrict__ xse,
        const __hip_bfloat16* __restrict__ e2vT,
        float* __restrict__ out) {
    __shared__ unsigned short As[128][136];
    __shared__ unsigned short Bs[64][136];
    const int tid = threadIdx.x;
    const int m0 = blockIdx.x * 128;   // row tile (8 tiles; x-fast => B-tile shared by adjacent blocks)
    const int v0 = blockIdx.y * 64;    // col tile (786 tiles)

    const unsigned short* gA = reinterpret_cast<const unsigned short*>(xse);
    const unsigned short* gB = reinterpret_cast<const unsigned short*>(e2vT);

    // stage A: 128 rows x 128 k, 16B chunks (8 bf16)
#pragma unroll
    for (int i = 0; i < 8; ++i) {
        const int c = tid + i * 256;
        const int row = c >> 4;
        const int kc = (c & 15) << 3;
        *reinterpret_cast<int4*>(&As[row][kc]) =
            *reinterpret_cast<const int4*>(gA + (size_t)(m0 + row) * E_DIM + kc);
    }
    // stage B: 64 rows (v) x 128 k
#pragma unroll
    for (int i = 0; i < 4; ++i) {
        const int c = tid + i * 256;
        const int row = c >> 4;
        const int kc = (c & 15) << 3;
        *reinterpret_cast<int4*>(&Bs[row][kc]) =
            *reinterpret_cast<const int4*>(gB + (size_t)(v0 + row) * E_DIM + kc);
    }
    __syncthreads();

    const int w = tid >> 6;       // wave 0..3 -> rows w*32 .. w*32+31
    const int lane = tid & 63;
    const int q = lane >> 4;      // 0..3
    const int l16 = lane & 15;
    const int wm = w * 32;

    float4v acc[2][4];
#pragma unroll
    for (int mi = 0; mi < 2; ++mi)
#pragma unroll
        for (int ni = 0; ni < 4; ++ni)
            acc[mi][ni] = (float4v){0.0f, 0.0f, 0.0f, 0.0f};

#pragma unroll
    for (int kk = 0; kk < 128; kk += 32) {
        const int ko = kk + q * 8;
        short8 a0 = *reinterpret_cast<const short8*>(&As[wm + l16][ko]);
        short8 a1 = *reinterpret_cast<const short8*>(&As[wm + 16 + l16][ko]);
#pragma unroll
        for (int ni = 0; ni < 4; ++ni) {
            short8 bf = *reinterpret_cast<const short8*>(&Bs[ni * 16 + l16][ko]);
            acc[0][ni] = __builtin_amdgcn_mfma_f32_16x16x32_bf16(a0, bf, acc[0][ni], 0, 0, 0);
            acc[1][ni] = __builtin_amdgcn_mfma_f32_16x16x32_bf16(a1, bf, acc[1][ni], 0, 0, 0);
        }
    }

    // C/D layout (m89-verified): col = lane&15, row = (lane>>4)*4 + reg
#pragma unroll
    for (int ni = 0; ni < 4; ++ni) {
        const int col = v0 + ni * 16 + l16;
        if (col < V_DIM) {
#pragma unroll
            for (int mi = 0; mi < 2; ++mi) {
                const int rbase = m0 + wm + mi * 16 + q * 4;
#pragma unroll
                for (int r = 0; r < 4; ++r)
                    out[(size_t)(rbase + r) * V_DIM + col] = acc[mi][ni][r];
            }
        }
    }
}

// ---------------------------------------------------------------------------
// K3: per-row logsumexp. stats[b] = max + log(sum exp(x - max))
// ---------------------------------------------------------------------------
__global__ void k3_lse(const float* __restrict__ logits,
                       float* __restrict__ stats) {
    const int b = blockIdx.x;
    const int tid = threadIdx.x;
    const size_t base = (size_t)b * V_DIM;

    float m = -INFINITY, s = 0.0f;
    auto upd = [&](float x) {
        if (x > m) { s = s * __expf(m - x) + 1.0f; m = x; }
        else       { s += __expf(x - m); }
    };

    const int h = (int)((4 - (base & 3)) & 3);
    if (tid < h) upd(logits[base + tid]);
    const int n4 = (V_DIM - h) >> 2;
    const float4* lv = reinterpret_cast<const float4*>(logits + base + h);
    for (int j = tid; j < n4; j += 256) {
        float4 x = lv[j];
        upd(x.x); upd(x.y); upd(x.z); upd(x.w);
    }
    for (int i = h + n4 * 4 + tid; i < V_DIM; i += 256) upd(logits[base + i]);

    __shared__ float rm[256], rs[256];
    rm[tid] = m; rs[tid] = s;
    __syncthreads();
    for (int off = 128; off > 0; off >>= 1) {
        if (tid < off) {
            const float m2 = rm[tid + off], s2 = rs[tid + off];
            const float M = fmaxf(m, m2);
            s = s * __expf(m - M) + s2 * __expf(m2 - M);
            m = M;
            rm[tid] = m; rs[tid] = s;
        }
        __syncthreads();
    }
    if (tid == 0) stats[b] = m + __logf(s);
}

// ---------------------------------------------------------------------------
// K4: out[b][v] -= stats[b], in place, float4 grid-stride.
// ---------------------------------------------------------------------------
__global__ void k4_norm(float* __restrict__ out,
                        const float* __restrict__ stats) {
    const unsigned total4 = (unsigned)((size_t)B_ROWS * V_DIM / 4);  // 12,865,792
    const unsigned stride = gridDim.x * blockDim.x;
    float4* o4 = reinterpret_cast<float4*>(out);
    for (unsigned i = blockIdx.x * blockDim.x + threadIdx.x; i < total4; i += stride) {
        float4 x = o4[i];
        const unsigned flat = i * 4u;
        const unsigned b0 = flat / V_DIM;          // constant divisor -> mulhi
        const unsigned r = flat - b0 * V_DIM;
        if (r + 3 < V_DIM) {
            const float l = stats[b0];
            x.x -= l; x.y -= l; x.z -= l; x.w -= l;
        } else {
            x.x -= stats[(flat + 0) / V_DIM];
            x.y -= stats[(flat + 1) / V_DIM];
            x.z -= stats[(flat + 2) / V_DIM];
            x.w -= stats[(flat + 3) / V_DIM];
        }
        o4[i] = x;
    }
}

// ---------------------------------------------------------------------------
extern "C" void kernel_launch(void* const* d_in, const int* in_sizes, int n_in,
                              void* d_out, int out_size, void* d_ws, size_t ws_size,
                              hipStream_t stream) {
    const float* xs  = (const float*)d_in[0];
    // d_in[1] = metric (unused by forward)
    const float* EM  = (const float*)d_in[2];
    const float* e2v = (const float*)d_in[3];
    float* out = (float*)d_out;

    char* ws = (char*)d_ws;
    __hip_bfloat16* e2vT = (__hip_bfloat16*)ws;                                // 12,877,824 B
    __hip_bfloat16* xse  = (__hip_bfloat16*)(ws + (size_t)V_PAD * E_DIM * 2);  // 262,144 B
    float* stats = (float*)(ws + (size_t)V_PAD * E_DIM * 2 + (size_t)B_ROWS * E_DIM * 2);  // 4 KB

    hipLaunchKernelGGL(k0_transpose, dim3(V_PAD / 32, E_DIM / 32), dim3(256), 0, stream, e2v, e2vT);
    hipLaunchKernelGGL(k1_embed, dim3(B_ROWS), dim3(256), 0, stream, xs, EM, xse);
    hipLaunchKernelGGL(k2_gemm, dim3(B_ROWS / 128, (V_DIM + 63) / 64), dim3(256), 0, stream, xse, e2vT, out);
    hipLaunchKernelGGL(k3_lse, dim3(B_ROWS), dim3(256), 0, stream, out, stats);
    hipLaunchKernelGGL(k4_norm, dim3(4096), dim3(256), 0, stream, out, stats);
}

// Round 2
// 460.366 us; speedup vs baseline: 1.0874x; 1.0874x over previous
//
#include <hip/hip_runtime.h>
#include <hip/hip_bf16.h>

#define B_ROWS 1024
#define V_DIM 50257
#define E_DIM 128
#define V_PAD 50304  // 786 * 64, >= V_DIM; GEMM tail tiles read zero-padding
#define NCT 786      // number of 64-wide col tiles

typedef __attribute__((ext_vector_type(8))) short short8;
typedef __attribute__((ext_vector_type(4))) float float4v;

// ---------------------------------------------------------------------------
// K0: transpose + cast embed2vocab [E][V] fp32 -> e2vT [V_PAD][E] bf16
// ---------------------------------------------------------------------------
__global__ void k0_transpose(const float* __restrict__ e2v,
                             __hip_bfloat16* __restrict__ e2vT) {
    __shared__ float t[32][33];
    const int v0 = blockIdx.x * 32;
    const int k0 = blockIdx.y * 32;
    const int c = threadIdx.x & 31;
    const int r = threadIdx.x >> 5;  // 0..7
#pragma unroll
    for (int i = 0; i < 4; ++i) {
        const int k = k0 + r + i * 8;
        const int v = v0 + c;
        t[r + i * 8][c] = (v < V_DIM) ? e2v[(size_t)k * V_DIM + v] : 0.0f;
    }
    __syncthreads();
#pragma unroll
    for (int i = 0; i < 4; ++i) {
        const int rv = r + i * 8;
        e2vT[(size_t)(v0 + rv) * E_DIM + k0 + c] = __float2bfloat16(t[c][rv]);
    }
}

// ---------------------------------------------------------------------------
// K1: xsembeds[b][:] = sum_v xs[b][v] * EMBEDM[v][:]   (xs rows have <=8 nnz)
// one block per row; scan row for nonzeros, then gather-accumulate.
// ---------------------------------------------------------------------------
__global__ void k1_embed(const float* __restrict__ xs,
                         const float* __restrict__ EM,
                         __hip_bfloat16* __restrict__ xse) {
    const int b = blockIdx.x;
    const int tid = threadIdx.x;
    __shared__ int nzv[64];
    __shared__ float nzval[64];
    __shared__ int nzcount;
    if (tid == 0) nzcount = 0;
    __syncthreads();

    const size_t base = (size_t)b * V_DIM;
    auto note = [&](int v, float val) {
        if (val != 0.0f) {
            int s = atomicAdd(&nzcount, 1);
            if (s < 64) { nzv[s] = v; nzval[s] = val; }
        }
    };

    const int h = (int)((4 - (base & 3)) & 3);
    if (tid < h) note(tid, xs[base + tid]);
    const int n4 = (V_DIM - h) >> 2;
    const float4* xv = reinterpret_cast<const float4*>(xs + base + h);
    for (int j = tid; j < n4; j += 256) {
        float4 x = xv[j];
        if (x.x != 0.0f || x.y != 0.0f || x.z != 0.0f || x.w != 0.0f) {
            const int v = h + 4 * j;
            note(v + 0, x.x);
            note(v + 1, x.y);
            note(v + 2, x.z);
            note(v + 3, x.w);
        }
    }
    for (int i = h + n4 * 4 + tid; i < V_DIM; i += 256) note(i, xs[base + i]);
    __syncthreads();

    int cnt = nzcount;
    if (cnt > 64) cnt = 64;
    if (tid < E_DIM) {
        float a = 0.0f;
        for (int s = 0; s < cnt; ++s)
            a += nzval[s] * EM[(size_t)nzv[s] * E_DIM + tid];
        xse[(size_t)b * E_DIM + tid] = __float2bfloat16(a);
    }
}

// ---------------------------------------------------------------------------
// Shared GEMM tile machinery: block = 128 rows x 64 cols, K = 128.
// 4 waves, each 32 rows x 64 cols. LDS stride 136 elems (272 B = 17*16 B):
// 16B-aligned b128 reads, 2-way bank aliasing only (free).
// C/D layout (m89-verified): col = lane&15, row = (lane>>4)*4 + reg.
// ---------------------------------------------------------------------------
#define GEMM_TILE_BODY(xse, e2vT)                                              \
    __shared__ unsigned short As[128][136];                                    \
    __shared__ unsigned short Bs[64][136];                                     \
    const int tid = threadIdx.x;                                               \
    const int m0 = blockIdx.x * 128;                                           \
    const int v0 = blockIdx.y * 64;                                            \
    const unsigned short* gA = reinterpret_cast<const unsigned short*>(xse);   \
    const unsigned short* gB = reinterpret_cast<const unsigned short*>(e2vT);  \
    _Pragma("unroll")                                                          \
    for (int i = 0; i < 8; ++i) {                                              \
        const int c = tid + i * 256;                                           \
        const int row = c >> 4;                                                \
        const int kc = (c & 15) << 3;                                          \
        *reinterpret_cast<int4*>(&As[row][kc]) =                               \
            *reinterpret_cast<const int4*>(gA + (size_t)(m0 + row) * E_DIM + kc); \
    }                                                                          \
    _Pragma("unroll")                                                          \
    for (int i = 0; i < 4; ++i) {                                              \
        const int c = tid + i * 256;                                           \
        const int row = c >> 4;                                                \
        const int kc = (c & 15) << 3;                                          \
        *reinterpret_cast<int4*>(&Bs[row][kc]) =                               \
            *reinterpret_cast<const int4*>(gB + (size_t)(v0 + row) * E_DIM + kc); \
    }                                                                          \
    __syncthreads();                                                           \
    const int w = tid >> 6;                                                    \
    const int lane = tid & 63;                                                 \
    const int q = lane >> 4;                                                   \
    const int l16 = lane & 15;                                                 \
    const int wm = w * 32;                                                     \
    float4v acc[2][4];                                                         \
    _Pragma("unroll")                                                          \
    for (int mi = 0; mi < 2; ++mi)                                             \
        _Pragma("unroll")                                                      \
        for (int ni = 0; ni < 4; ++ni)                                         \
            acc[mi][ni] = (float4v){0.0f, 0.0f, 0.0f, 0.0f};                   \
    _Pragma("unroll")                                                          \
    for (int kk = 0; kk < 128; kk += 32) {                                     \
        const int ko = kk + q * 8;                                             \
        short8 a0 = *reinterpret_cast<const short8*>(&As[wm + l16][ko]);       \
        short8 a1 = *reinterpret_cast<const short8*>(&As[wm + 16 + l16][ko]);  \
        _Pragma("unroll")                                                      \
        for (int ni = 0; ni < 4; ++ni) {                                       \
            short8 bf = *reinterpret_cast<const short8*>(&Bs[ni * 16 + l16][ko]); \
            acc[0][ni] = __builtin_amdgcn_mfma_f32_16x16x32_bf16(a0, bf, acc[0][ni], 0, 0, 0); \
            acc[1][ni] = __builtin_amdgcn_mfma_f32_16x16x32_bf16(a1, bf, acc[1][ni], 0, 0, 0); \
        }                                                                      \
    }

// ---------------------------------------------------------------------------
// KB pass 1: GEMM tile -> per-row (max, sumexp) partials. No logit store.
// ---------------------------------------------------------------------------
__global__ __launch_bounds__(256) void kb_pass1(
        const __hip_bfloat16* __restrict__ xse,
        const __hip_bfloat16* __restrict__ e2vT,
        float* __restrict__ pmax,
        float* __restrict__ psum) {
    GEMM_TILE_BODY(xse, e2vT)

#pragma unroll
    for (int mi = 0; mi < 2; ++mi) {
#pragma unroll
        for (int r = 0; r < 4; ++r) {
            float mx = -INFINITY;
#pragma unroll
            for (int ni = 0; ni < 4; ++ni) {
                const int col = v0 + ni * 16 + l16;
                const float x = (col < V_DIM) ? acc[mi][ni][r] : -INFINITY;
                mx = fmaxf(mx, x);
            }
            // reduce across the 16-lane column group (lanes sharing q)
            mx = fmaxf(mx, __shfl_xor(mx, 1));
            mx = fmaxf(mx, __shfl_xor(mx, 2));
            mx = fmaxf(mx, __shfl_xor(mx, 4));
            mx = fmaxf(mx, __shfl_xor(mx, 8));
            float s = 0.0f;
#pragma unroll
            for (int ni = 0; ni < 4; ++ni) {
                const int col = v0 + ni * 16 + l16;
                const float x = (col < V_DIM) ? acc[mi][ni][r] : -INFINITY;
                s += __expf(x - mx);  // exp(-inf) = 0 for masked cols
            }
            s += __shfl_xor(s, 1);
            s += __shfl_xor(s, 2);
            s += __shfl_xor(s, 4);
            s += __shfl_xor(s, 8);
            if (l16 == 0) {
                const int row = m0 + wm + mi * 16 + q * 4 + r;
                pmax[(size_t)row * NCT + blockIdx.y] = mx;
                psum[(size_t)row * NCT + blockIdx.y] = s;
            }
        }
    }
}

// ---------------------------------------------------------------------------
// KC: combine 786 partials per row -> stats[b] = logsumexp of the row
// ---------------------------------------------------------------------------
__global__ void kc_combine(const float* __restrict__ pmax,
                           const float* __restrict__ psum,
                           float* __restrict__ stats) {
    const int b = blockIdx.x;
    const int tid = threadIdx.x;
    float m = -INFINITY, s = 0.0f;
    for (int j = tid; j < NCT; j += 256) {
        const float mj = pmax[(size_t)b * NCT + j];
        const float sj = psum[(size_t)b * NCT + j];
        if (mj > m) { s = s * __expf(m - mj) + sj; m = mj; }
        else        { s += sj * __expf(mj - m); }
    }
    __shared__ float rm[256], rs[256];
    rm[tid] = m; rs[tid] = s;
    __syncthreads();
    for (int off = 128; off > 0; off >>= 1) {
        if (tid < off) {
            const float m2 = rm[tid + off], s2 = rs[tid + off];
            const float M = fmaxf(m, m2);
            s = s * __expf(m - M) + s2 * __expf(m2 - M);
            m = M;
            rm[tid] = m; rs[tid] = s;
        }
        __syncthreads();
    }
    if (tid == 0) stats[b] = m + __logf(s);
}

// ---------------------------------------------------------------------------
// KD pass 2: recompute GEMM tile, subtract lse, store final output (once).
// ---------------------------------------------------------------------------
__global__ __launch_bounds__(256) void kd_pass2(
        const __hip_bfloat16* __restrict__ xse,
        const __hip_bfloat16* __restrict__ e2vT,
        const float* __restrict__ stats,
        float* __restrict__ out) {
    GEMM_TILE_BODY(xse, e2vT)

#pragma unroll
    for (int mi = 0; mi < 2; ++mi) {
        const int rbase = m0 + wm + mi * 16 + q * 4;
        float l[4];
#pragma unroll
        for (int r = 0; r < 4; ++r) l[r] = stats[rbase + r];
#pragma unroll
        for (int ni = 0; ni < 4; ++ni) {
            const int col = v0 + ni * 16 + l16;
            if (col < V_DIM) {
#pragma unroll
                for (int r = 0; r < 4; ++r)
                    out[(size_t)(rbase + r) * V_DIM + col] = acc[mi][ni][r] - l[r];
            }
        }
    }
}

// ---------------------------------------------------------------------------
extern "C" void kernel_launch(void* const* d_in, const int* in_sizes, int n_in,
                              void* d_out, int out_size, void* d_ws, size_t ws_size,
                              hipStream_t stream) {
    const float* xs  = (const float*)d_in[0];
    // d_in[1] = metric (unused by forward)
    const float* EM  = (const float*)d_in[2];
    const float* e2v = (const float*)d_in[3];
    float* out = (float*)d_out;

    char* ws = (char*)d_ws;
    __hip_bfloat16* e2vT = (__hip_bfloat16*)ws;                         // 12,877,824 B
    size_t off = (size_t)V_PAD * E_DIM * 2;
    __hip_bfloat16* xse = (__hip_bfloat16*)(ws + off);                  // 262,144 B
    off += (size_t)B_ROWS * E_DIM * 2;
    float* pmax = (float*)(ws + off);                                   // 3,219,456 B
    off += (size_t)B_ROWS * NCT * 4;
    float* psum = (float*)(ws + off);                                   // 3,219,456 B
    off += (size_t)B_ROWS * NCT * 4;
    float* stats = (float*)(ws + off);                                  // 4,096 B

    hipLaunchKernelGGL(k0_transpose, dim3(V_PAD / 32, E_DIM / 32), dim3(256), 0, stream, e2v, e2vT);
    hipLaunchKernelGGL(k1_embed, dim3(B_ROWS), dim3(256), 0, stream, xs, EM, xse);
    hipLaunchKernelGGL(kb_pass1, dim3(B_ROWS / 128, NCT), dim3(256), 0, stream, xse, e2vT, pmax, psum);
    hipLaunchKernelGGL(kc_combine, dim3(B_ROWS), dim3(256), 0, stream, pmax, psum, stats);
    hipLaunchKernelGGL(kd_pass2, dim3(B_ROWS / 128, NCT), dim3(256), 0, stream, xse, e2vT, stats, out);
}